// Round 7
// baseline (187.827 us; speedup 1.0000x reference)
//
#include <hip/hip_runtime.h>
#include <cstdint>
#include <cstddef>

// ---------------- types ----------------
typedef __bf16 bf16x8 __attribute__((ext_vector_type(8)));
typedef __bf16 bf16x4 __attribute__((ext_vector_type(4)));
typedef float  f32x4  __attribute__((ext_vector_type(4)));

#define DIMD 1024
#define SEQ  2048
#define NB   2
#define NH   16
#define HD   64
#define QKVN 1536   // 1024 + 2*256
#define VOFF 1280   // DIMD + 256
#define VSTR 2080   // padded V^T row stride (4160B: breaks L2 channel aliasing)
#define CSC  0.18033688011112042f   // 0.125 * log2(e), folded into q in GEMM1

// async global->LDS (16B per lane, wave-uniform LDS base)
typedef __attribute__((address_space(1))) const void* as1_cvp;
typedef __attribute__((address_space(3))) void* as3_vp;
#define GLL16(g, l) __builtin_amdgcn_global_load_lds((as1_cvp)(const void*)(g), (as3_vp)(void*)(l), 16, 0, 0)

// ---------------- fp32 -> bf16 elementwise (vec4) ----------------
__global__ void cvt_f32_bf16(const float* __restrict__ in, __bf16* __restrict__ out, int n4) {
    int i = blockIdx.x * blockDim.x + threadIdx.x;
    if (i >= n4) return;
    float4 v = reinterpret_cast<const float4*>(in)[i];
    bf16x4 o;
    o[0] = (__bf16)v.x; o[1] = (__bf16)v.y; o[2] = (__bf16)v.z; o[3] = (__bf16)v.w;
    reinterpret_cast<bf16x4*>(out)[i] = o;
}

// ---------------- fp32 [R][C] -> bf16 [C][R] tiled transpose ----------------
__global__ void transpose_cvt(const float* __restrict__ in, __bf16* __restrict__ out, int R, int C) {
    __shared__ float t[32][33];
    int bx = blockIdx.x * 32;
    int by = blockIdx.y * 32;
    int tx = threadIdx.x, ty = threadIdx.y;   // (32, 8)
#pragma unroll
    for (int i = 0; i < 32; i += 8)
        t[ty + i][tx] = in[(size_t)(by + ty + i) * C + bx + tx];
    __syncthreads();
#pragma unroll
    for (int i = 0; i < 32; i += 8)
        out[(size_t)(bx + ty + i) * R + by + tx] = (__bf16)t[tx][ty + i];
}

// ---------------- bf16 [S][64] V-slice of qkv -> bf16 Vt[z][64][VSTR] ----------------
__global__ void transpose_v(const __bf16* __restrict__ qkv, __bf16* __restrict__ vtg) {
    __shared__ __bf16 t[32][34];
    const int z = blockIdx.z;           // b*4 + kh
    const int b = z >> 2, kh = z & 3;
    const int s0 = blockIdx.x * 32, d0 = blockIdx.y * 32;
    const int tx = threadIdx.x, ty = threadIdx.y;   // (32, 8)
    const __bf16* src = qkv + (size_t)b * SEQ * QKVN + VOFF + kh * HD;
#pragma unroll
    for (int i = 0; i < 32; i += 8)
        t[ty + i][tx] = src[(size_t)(s0 + ty + i) * QKVN + d0 + tx];
    __syncthreads();
    __bf16* dst = vtg + ((size_t)z * HD + d0) * VSTR + s0;
#pragma unroll
    for (int i = 0; i < 32; i += 8)
        dst[(size_t)(ty + i) * VSTR + tx] = t[tx][ty + i];
}

// ---------------- bf16 GEMM (m97 structure): C[M,N] = A[M,K]*Bt[N,K]^T + bias ----
// QSCALE: multiply cols < 1024 by CSC (pre-scales q for the attention kernel).
template<int OUT_BF16, int QSCALE>
__global__ __launch_bounds__(256) void gemm_bf16(
    const __bf16* __restrict__ A, const __bf16* __restrict__ Bt,
    const float* __restrict__ bias, void* __restrict__ Cout,
    int M, int N, int K)
{
    __shared__ __bf16 Als[128 * 32];   // linear: row*32 + k  (64B rows -> conflict-free b128)
    __shared__ __bf16 Bls[128 * 32];
    const int tid  = threadIdx.x;
    const int lane = tid & 63;
    const int wave = tid >> 6;
    const int lo = lane & 15, hi = lane >> 4;
    const int bm = blockIdx.y * 128, bn = blockIdx.x * 128;
    const int wr = (wave >> 1) * 64, wc = (wave & 1) * 64;

    const __bf16* gA = A  + (size_t)(bm + wave * 32 + (lane >> 2)) * K + (lane & 3) * 8;
    const __bf16* gB = Bt + (size_t)(bn + wave * 32 + (lane >> 2)) * K + (lane & 3) * 8;
    __bf16* lA = &Als[wave * 32 * 32];
    __bf16* lB = &Bls[wave * 32 * 32];

    f32x4 acc[4][4] = {};

    for (int k0 = 0; k0 < K; k0 += 32) {
        __syncthreads();
        GLL16(gA + k0,                  lA);
        GLL16(gA + k0 + (size_t)16 * K, lA + 512);
        GLL16(gB + k0,                  lB);
        GLL16(gB + k0 + (size_t)16 * K, lB + 512);
        __syncthreads();

        bf16x8 af[4], bfr[4];
#pragma unroll
        for (int i = 0; i < 4; i++) {
            af[i]  = *reinterpret_cast<const bf16x8*>(&Als[(wr + i * 16 + lo) * 32 + hi * 8]);
            bfr[i] = *reinterpret_cast<const bf16x8*>(&Bls[(wc + i * 16 + lo) * 32 + hi * 8]);
        }
#pragma unroll
        for (int i = 0; i < 4; i++)
#pragma unroll
            for (int j = 0; j < 4; j++)
                acc[i][j] = __builtin_amdgcn_mfma_f32_16x16x32_bf16(af[i], bfr[j], acc[i][j], 0, 0, 0);
    }

#pragma unroll
    for (int j = 0; j < 4; j++) {
        int col = bn + wc + j * 16 + lo;
        float bv = bias[col];
#pragma unroll
        for (int i = 0; i < 4; i++) {
            int row0 = bm + wr + i * 16 + hi * 4;
#pragma unroll
            for (int rr = 0; rr < 4; rr++) {
                float v = acc[i][j][rr] + bv;
                if (QSCALE && col < DIMD) v *= CSC;
                if (OUT_BF16) ((__bf16*)Cout)[(size_t)(row0 + rr) * N + col] = (__bf16)v;
                else          ((float* )Cout)[(size_t)(row0 + rr) * N + col] = v;
            }
        }
    }
}

// ---------------- causal GQA flash attention ----------------
// 1D grid 1024, 256 threads = 4 waves = the 4 q-heads of one kv-group, all on
// the SAME 16-row q-tile (identical work + identical K/V lines -> L1 sharing).
// bid&7 = b*4+kh pins each kv-group's K/V to one XCD's L2 (round-robin dispatch).
// Heavy tiles first (T = 127 - bid>>3) for backfill. Swapped QK^T (S^T=K·Q),
// fixed-max exp2 softmax (scores pre-scaled by CSC in GEMM1), per-wave P in LDS.
// Steady-state chunks have NO masking; diag chunk peeled (static lane predicate).
__global__ __launch_bounds__(256) void attn_fwd(
    const __bf16* __restrict__ qkv, const __bf16* __restrict__ vt, __bf16* __restrict__ y)
{
    __shared__ __bf16 Pls[4][16][72];    // per-wave P[q][k], 144B rows
    const int tid  = threadIdx.x;
    const int wave = tid >> 6, lane = tid & 63;
    const int lo = lane & 15, hi = lane >> 4;

    const int bid = blockIdx.x;
    const int z  = bid & 7;              // b*4 + kh  -> XCD-pinned
    const int b  = z >> 2, kh = z & 3;
    const int T  = 127 - (bid >> 3);     // 16-row tile index, heavy first
    const int h  = kh * 4 + wave;        // wave = head within kv-group
    const int qw = T * 16;
    const int j  = T & 3;                // live k-subtiles in diag chunk: 0..j
    const int ktd = (T >> 2) * 64;       // diag chunk base

    const __bf16* base = qkv + (size_t)b * SEQ * QKVN;
    const __bf16* qp = base + h * HD;
    const __bf16* kp = base + DIMD + kh * HD;
    const __bf16* vp = vt + (size_t)z * HD * VSTR;   // [64][VSTR]

    // Q B-frags: lane holds Q[qw+lo][hi*8..+8] (pre-scaled by CSC in GEMM1)
    bf16x8 bQ0 = *reinterpret_cast<const bf16x8*>(qp + (size_t)(qw + lo) * QKVN + hi * 8);
    bf16x8 bQ1 = *reinterpret_cast<const bf16x8*>(qp + (size_t)(qw + lo) * QKVN + 32 + hi * 8);

    f32x4 accO[4] = {};
    float ssum = 0.0f;   // partial row-sum for q = qw+lo over this lane's keys

    // ---- steady-state chunks: no masking at all ----
    for (int kt = 0; kt < ktd; kt += 64) {
        // V B-frags first (independent of QK; overlap their latency)
        bf16x8 vB[8];
#pragma unroll
        for (int k2 = 0; k2 < 2; k2++)
#pragma unroll
            for (int f = 0; f < 4; f++)
                vB[k2 * 4 + f] = *reinterpret_cast<const bf16x8*>(
                    vp + (size_t)(f * 16 + lo) * VSTR + kt + k2 * 32 + hi * 8);

        // S^T = K Q^T : lane gets q=lo, k=kt+16ks+hi*4+r
#pragma unroll
        for (int ks = 0; ks < 4; ks++) {
            const __bf16* kr = kp + (size_t)(kt + ks * 16 + lo) * QKVN + hi * 8;
            bf16x8 aK0 = *reinterpret_cast<const bf16x8*>(kr);
            bf16x8 aK1 = *reinterpret_cast<const bf16x8*>(kr + 32);
            f32x4 s = {0.f, 0.f, 0.f, 0.f};
            s = __builtin_amdgcn_mfma_f32_16x16x32_bf16(aK0, bQ0, s, 0, 0, 0);
            s = __builtin_amdgcn_mfma_f32_16x16x32_bf16(aK1, bQ1, s, 0, 0, 0);
            bf16x4 pk;
#pragma unroll
            for (int r = 0; r < 4; r++) {
                float e = exp2f(s[r]);
                ssum += e;
                pk[r] = (__bf16)e;
            }
            *reinterpret_cast<bf16x4*>(&Pls[wave][lo][ks * 16 + hi * 4]) = pk;
        }

        // P x V
#pragma unroll
        for (int k2 = 0; k2 < 2; k2++) {
            bf16x8 pA = *reinterpret_cast<const bf16x8*>(&Pls[wave][lo][k2 * 32 + hi * 8]);
#pragma unroll
            for (int f = 0; f < 4; f++)
                accO[f] = __builtin_amdgcn_mfma_f32_16x16x32_bf16(pA, vB[k2 * 4 + f], accO[f], 0, 0, 0);
        }
    }

    // ---- diagonal chunk (peeled): subtiles 0..j-1 full, j masked, rest dead ----
    {
        const int kt = ktd;
        const int k2max  = j >> 1;           // PV halves 0..k2max
        const int ksNeed = 2 * k2max + 1;    // P must be valid through this subtile

        bf16x8 vB[8];
#pragma unroll
        for (int k2 = 0; k2 < 2; k2++) {
            if (k2 > k2max) continue;
#pragma unroll
            for (int f = 0; f < 4; f++)
                vB[k2 * 4 + f] = *reinterpret_cast<const bf16x8*>(
                    vp + (size_t)(f * 16 + lo) * VSTR + kt + k2 * 32 + hi * 8);
        }

#pragma unroll
        for (int ks = 0; ks < 4; ks++) {
            if (ks > ksNeed) continue;
            bf16x4 pk = {(__bf16)0.f, (__bf16)0.f, (__bf16)0.f, (__bf16)0.f};
            if (ks <= j) {
                const __bf16* kr = kp + (size_t)(kt + ks * 16 + lo) * QKVN + hi * 8;
                bf16x8 aK0 = *reinterpret_cast<const bf16x8*>(kr);
                bf16x8 aK1 = *reinterpret_cast<const bf16x8*>(kr + 32);
                f32x4 s = {0.f, 0.f, 0.f, 0.f};
                s = __builtin_amdgcn_mfma_f32_16x16x32_bf16(aK0, bQ0, s, 0, 0, 0);
                s = __builtin_amdgcn_mfma_f32_16x16x32_bf16(aK1, bQ1, s, 0, 0, 0);
                const bool atDiag = (ks == j);
#pragma unroll
                for (int r = 0; r < 4; r++) {
                    float e = exp2f(s[r]);
                    if (atDiag && (hi * 4 + r > lo)) e = 0.0f;   // k - q = hi*4+r - lo
                    ssum += e;
                    pk[r] = (__bf16)e;
                }
            }
            *reinterpret_cast<bf16x4*>(&Pls[wave][lo][ks * 16 + hi * 4]) = pk;
        }

#pragma unroll
        for (int k2 = 0; k2 < 2; k2++) {
            if (k2 > k2max) continue;
            bf16x8 pA = *reinterpret_cast<const bf16x8*>(&Pls[wave][lo][k2 * 32 + hi * 8]);
#pragma unroll
            for (int f = 0; f < 4; f++)
                accO[f] = __builtin_amdgcn_mfma_f32_16x16x32_bf16(pA, vB[k2 * 4 + f], accO[f], 0, 0, 0);
        }
    }

    // full row-sum for q=qw+lo (combine the 4 hi-groups), then redistribute:
    // accO lane holds q = qw + hi*4 + r, d = f*16 + lo.
    ssum += __shfl_xor(ssum, 16);
    ssum += __shfl_xor(ssum, 32);
#pragma unroll
    for (int r = 0; r < 4; r++) {
        float sr = __shfl(ssum, hi * 4 + r);   // lane with lo == hi*4+r, hi==0 has it
        float inv = 1.0f / sr;
        int q = qw + hi * 4 + r;
#pragma unroll
        for (int f = 0; f < 4; f++) {
            float val = accO[f][r] * inv;
            y[(size_t)(b * SEQ + q) * DIMD + h * HD + f * 16 + lo] = (__bf16)val;
        }
    }
}

// ---------------- launcher ----------------
extern "C" void kernel_launch(void* const* d_in, const int* in_sizes, int n_in,
                              void* d_out, int out_size, void* d_ws, size_t ws_size,
                              hipStream_t stream) {
    const float* x    = (const float*)d_in[0];
    const float* Wqkv = (const float*)d_in[1];
    const float* bqkv = (const float*)d_in[2];
    const float* Wout = (const float*)d_in[3];
    const float* bout = (const float*)d_in[4];
    float* out = (float*)d_out;

    char* ws = (char*)d_ws;
    __bf16* xb    = (__bf16*)(ws);                          // 8 MB  (x bf16; later reused as y)
    __bf16* wqkvT = (__bf16*)(ws + ((size_t)8  << 20));     // 3 MB  [1536][1024] (dead after GEMM1)
    __bf16* woutT = (__bf16*)(ws + ((size_t)11 << 20));     // 2 MB  [1024][1024]
    __bf16* qkvb  = (__bf16*)(ws + ((size_t)13 << 20));     // 12 MB [4096][1536]
    __bf16* vtg   = wqkvT;                                  // alias: 2.2 MB Vt[8][64][VSTR]
    __bf16* yb    = xb;                                     // alias: xb dead after GEMM1

    const int M = NB * SEQ;   // 4096

    cvt_f32_bf16<<<(M * DIMD / 4 + 255) / 256, 256, 0, stream>>>(x, xb, M * DIMD / 4);
    transpose_cvt<<<dim3(QKVN / 32, DIMD / 32), dim3(32, 8), 0, stream>>>(Wqkv, wqkvT, DIMD, QKVN);
    transpose_cvt<<<dim3(DIMD / 32, DIMD / 32), dim3(32, 8), 0, stream>>>(Wout, woutT, DIMD, DIMD);

    gemm_bf16<1, 1><<<dim3(QKVN / 128, M / 128), 256, 0, stream>>>(xb, wqkvT, bqkv, qkvb, M, QKVN, DIMD);

    transpose_v<<<dim3(SEQ / 32, HD / 32, NB * 4), dim3(32, 8), 0, stream>>>(qkvb, vtg);

    attn_fwd<<<1024, 256, 0, stream>>>(qkvb, vtg, yb);

    gemm_bf16<0, 0><<<dim3(DIMD / 128, M / 128), 256, 0, stream>>>(yb, woutT, bout, out, M, DIMD, DIMD);
}

// Round 8
// 158.557 us; speedup vs baseline: 1.1846x; 1.1846x over previous
//
#include <hip/hip_runtime.h>
#include <cstdint>
#include <cstddef>

// ---------------- types ----------------
typedef __bf16 bf16x8 __attribute__((ext_vector_type(8)));
typedef __bf16 bf16x4 __attribute__((ext_vector_type(4)));
typedef float  f32x4  __attribute__((ext_vector_type(4)));

#define DIMD 1024
#define SEQ  2048
#define NB   2
#define NH   16
#define HD   64
#define QKVN 1536   // 1024 + 2*256
#define VOFF 1280   // DIMD + 256
#define VSTR 2080   // padded V^T row stride (4160B: breaks L2 channel aliasing)
#define CSC  0.18033688011112042f   // 0.125 * log2(e), folded into q in GEMM1

// async global->LDS (16B per lane, wave-uniform LDS base)
typedef __attribute__((address_space(1))) const void* as1_cvp;
typedef __attribute__((address_space(3))) void* as3_vp;
#define GLL16(g, l) __builtin_amdgcn_global_load_lds((as1_cvp)(const void*)(g), (as3_vp)(void*)(l), 16, 0, 0)

// ---------------- fp32 -> bf16 elementwise (vec4) ----------------
__global__ void cvt_f32_bf16(const float* __restrict__ in, __bf16* __restrict__ out, int n4) {
    int i = blockIdx.x * blockDim.x + threadIdx.x;
    if (i >= n4) return;
    float4 v = reinterpret_cast<const float4*>(in)[i];
    bf16x4 o;
    o[0] = (__bf16)v.x; o[1] = (__bf16)v.y; o[2] = (__bf16)v.z; o[3] = (__bf16)v.w;
    reinterpret_cast<bf16x4*>(out)[i] = o;
}

// ---------------- fp32 [R][C] -> bf16 [C][R] tiled transpose ----------------
__global__ void transpose_cvt(const float* __restrict__ in, __bf16* __restrict__ out, int R, int C) {
    __shared__ float t[32][33];
    int bx = blockIdx.x * 32;
    int by = blockIdx.y * 32;
    int tx = threadIdx.x, ty = threadIdx.y;   // (32, 8)
#pragma unroll
    for (int i = 0; i < 32; i += 8)
        t[ty + i][tx] = in[(size_t)(by + ty + i) * C + bx + tx];
    __syncthreads();
#pragma unroll
    for (int i = 0; i < 32; i += 8)
        out[(size_t)(bx + ty + i) * R + by + tx] = (__bf16)t[tx][ty + i];
}

// ---------------- bf16 [S][64] V-slice of qkv -> bf16 Vt[z][64][VSTR] ----------------
__global__ void transpose_v(const __bf16* __restrict__ qkv, __bf16* __restrict__ vtg) {
    __shared__ __bf16 t[32][34];
    const int z = blockIdx.z;           // b*4 + kh
    const int b = z >> 2, kh = z & 3;
    const int s0 = blockIdx.x * 32, d0 = blockIdx.y * 32;
    const int tx = threadIdx.x, ty = threadIdx.y;   // (32, 8)
    const __bf16* src = qkv + (size_t)b * SEQ * QKVN + VOFF + kh * HD;
#pragma unroll
    for (int i = 0; i < 32; i += 8)
        t[ty + i][tx] = src[(size_t)(s0 + ty + i) * QKVN + d0 + tx];
    __syncthreads();
    __bf16* dst = vtg + ((size_t)z * HD + d0) * VSTR + s0;
#pragma unroll
    for (int i = 0; i < 32; i += 8)
        dst[(size_t)(ty + i) * VSTR + tx] = t[tx][ty + i];
}

// ---------------- bf16 GEMM (m97 structure): C[M,N] = A[M,K]*Bt[N,K]^T + bias ----
// QSCALE: multiply cols < 1024 by CSC (pre-scales q for the attention kernel).
template<int OUT_BF16, int QSCALE>
__global__ __launch_bounds__(256) void gemm_bf16(
    const __bf16* __restrict__ A, const __bf16* __restrict__ Bt,
    const float* __restrict__ bias, void* __restrict__ Cout,
    int M, int N, int K)
{
    __shared__ __bf16 Als[128 * 32];   // linear: row*32 + k  (64B rows -> conflict-free b128)
    __shared__ __bf16 Bls[128 * 32];
    const int tid  = threadIdx.x;
    const int lane = tid & 63;
    const int wave = tid >> 6;
    const int lo = lane & 15, hi = lane >> 4;
    const int bm = blockIdx.y * 128, bn = blockIdx.x * 128;
    const int wr = (wave >> 1) * 64, wc = (wave & 1) * 64;

    const __bf16* gA = A  + (size_t)(bm + wave * 32 + (lane >> 2)) * K + (lane & 3) * 8;
    const __bf16* gB = Bt + (size_t)(bn + wave * 32 + (lane >> 2)) * K + (lane & 3) * 8;
    __bf16* lA = &Als[wave * 32 * 32];
    __bf16* lB = &Bls[wave * 32 * 32];

    f32x4 acc[4][4] = {};

    for (int k0 = 0; k0 < K; k0 += 32) {
        __syncthreads();
        GLL16(gA + k0,                  lA);
        GLL16(gA + k0 + (size_t)16 * K, lA + 512);
        GLL16(gB + k0,                  lB);
        GLL16(gB + k0 + (size_t)16 * K, lB + 512);
        __syncthreads();

        bf16x8 af[4], bfr[4];
#pragma unroll
        for (int i = 0; i < 4; i++) {
            af[i]  = *reinterpret_cast<const bf16x8*>(&Als[(wr + i * 16 + lo) * 32 + hi * 8]);
            bfr[i] = *reinterpret_cast<const bf16x8*>(&Bls[(wc + i * 16 + lo) * 32 + hi * 8]);
        }
#pragma unroll
        for (int i = 0; i < 4; i++)
#pragma unroll
            for (int j = 0; j < 4; j++)
                acc[i][j] = __builtin_amdgcn_mfma_f32_16x16x32_bf16(af[i], bfr[j], acc[i][j], 0, 0, 0);
    }

#pragma unroll
    for (int j = 0; j < 4; j++) {
        int col = bn + wc + j * 16 + lo;
        float bv = bias[col];
#pragma unroll
        for (int i = 0; i < 4; i++) {
            int row0 = bm + wr + i * 16 + hi * 4;
#pragma unroll
            for (int rr = 0; rr < 4; rr++) {
                float v = acc[i][j][rr] + bv;
                if (QSCALE && col < DIMD) v *= CSC;
                if (OUT_BF16) ((__bf16*)Cout)[(size_t)(row0 + rr) * N + col] = (__bf16)v;
                else          ((float* )Cout)[(size_t)(row0 + rr) * N + col] = v;
            }
        }
    }
}

// ---------------- causal GQA flash attention (paired dual-tile waves) ----------------
// 1D grid 512, 256 threads = 4 waves = the 4 q-heads of one kv-group. bid&7 =
// b*4+kh pins K/V to one XCD's L2. Each wave processes TWO 16-row q-tiles,
// A = p and B = 127-p, INTERLEAVED in one chunk loop: every wave everywhere does
// exactly 33 chunk-computations (equal work), and in the shared prefix the two
// tiles reuse the same K/V fragments (2x ILP, loads amortized). Swapped QK^T
// (S^T = K*Q), fixed-max exp2 softmax (scores pre-scaled by CSC in GEMM1).
// Masking evaluated only on each tile's diagonal chunk (wave-uniform flag);
// dead subtiles there are computed-and-masked (cheap, <=1 wasted chunk).
__global__ __launch_bounds__(256) void attn_fwd(
    const __bf16* __restrict__ qkv, const __bf16* __restrict__ vt, __bf16* __restrict__ y)
{
    __shared__ __bf16 Pls[4][2][16][72];   // [wave][tile][q][k], 144B rows
    const int tid  = threadIdx.x;
    const int wave = tid >> 6, lane = tid & 63;
    const int lo = lane & 15, hi = lane >> 4;

    const int bid = blockIdx.x;
    const int z  = bid & 7;              // b*4 + kh  -> XCD-pinned
    const int b  = z >> 2, kh = z & 3;
    const int p  = bid >> 3;             // 0..63
    const int h  = kh * 4 + wave;        // wave = head within kv-group

    const int TA = p, TB = 127 - p;
    const int qwA = TA * 16, qwB = TB * 16;
    const int cA = (TA >> 2) + 1, cB = (TB >> 2) + 1;   // cA <= 16 < 17 <= cB

    const __bf16* base = qkv + (size_t)b * SEQ * QKVN;
    const __bf16* qp = base + h * HD;
    const __bf16* kp = base + DIMD + kh * HD;
    const __bf16* vp = vt + (size_t)z * HD * VSTR;      // [64][VSTR]

    // Q B-frags (pre-scaled by CSC in GEMM1): lane holds Q[qw+lo][hi*8..+8]
    bf16x8 bQA0 = *reinterpret_cast<const bf16x8*>(qp + (size_t)(qwA + lo) * QKVN + hi * 8);
    bf16x8 bQA1 = *reinterpret_cast<const bf16x8*>(qp + (size_t)(qwA + lo) * QKVN + 32 + hi * 8);
    bf16x8 bQB0 = *reinterpret_cast<const bf16x8*>(qp + (size_t)(qwB + lo) * QKVN + hi * 8);
    bf16x8 bQB1 = *reinterpret_cast<const bf16x8*>(qp + (size_t)(qwB + lo) * QKVN + 32 + hi * 8);

    f32x4 accA[4] = {}, accB[4] = {};
    float ssA = 0.0f, ssB = 0.0f;

    for (int c = 0; c < cB; ++c) {
        const int kt = c << 6;
        const bool aA = (c < cA);          // tile A active this chunk
        const bool dA = (c == cA - 1);     // tile A diagonal chunk
        const bool dB = (c == cB - 1);     // tile B diagonal chunk

        // V B-frags first (shared by both tiles; latency hides under QK/softmax)
        bf16x8 vB[8];
#pragma unroll
        for (int k2 = 0; k2 < 2; k2++)
#pragma unroll
            for (int f = 0; f < 4; f++)
                vB[k2 * 4 + f] = *reinterpret_cast<const bf16x8*>(
                    vp + (size_t)(f * 16 + lo) * VSTR + kt + k2 * 32 + hi * 8);

        // S^T = K Q^T per 16-key subtile; lane gets q=lo, k = kt+16ks+hi*4+r
#pragma unroll
        for (int ks = 0; ks < 4; ks++) {
            const __bf16* kr = kp + (size_t)(kt + ks * 16 + lo) * QKVN + hi * 8;
            bf16x8 aK0 = *reinterpret_cast<const bf16x8*>(kr);
            bf16x8 aK1 = *reinterpret_cast<const bf16x8*>(kr + 32);

            {   // tile B (always active)
                f32x4 s = {0.f, 0.f, 0.f, 0.f};
                s = __builtin_amdgcn_mfma_f32_16x16x32_bf16(aK0, bQB0, s, 0, 0, 0);
                s = __builtin_amdgcn_mfma_f32_16x16x32_bf16(aK1, bQB1, s, 0, 0, 0);
                bf16x4 pk;
#pragma unroll
                for (int r = 0; r < 4; r++) {
                    float e = exp2f(s[r]);
                    if (dB && (kt + ks * 16 + hi * 4 + r > qwB + lo)) e = 0.0f;
                    ssB += e;
                    pk[r] = (__bf16)e;
                }
                *reinterpret_cast<bf16x4*>(&Pls[wave][1][lo][ks * 16 + hi * 4]) = pk;
            }
            if (aA) {   // tile A (prefix only) — reuses aK0/aK1
                f32x4 s = {0.f, 0.f, 0.f, 0.f};
                s = __builtin_amdgcn_mfma_f32_16x16x32_bf16(aK0, bQA0, s, 0, 0, 0);
                s = __builtin_amdgcn_mfma_f32_16x16x32_bf16(aK1, bQA1, s, 0, 0, 0);
                bf16x4 pk;
#pragma unroll
                for (int r = 0; r < 4; r++) {
                    float e = exp2f(s[r]);
                    if (dA && (kt + ks * 16 + hi * 4 + r > qwA + lo)) e = 0.0f;
                    ssA += e;
                    pk[r] = (__bf16)e;
                }
                *reinterpret_cast<bf16x4*>(&Pls[wave][0][lo][ks * 16 + hi * 4]) = pk;
            }
        }

        // P x V (V frags shared by both tiles)
#pragma unroll
        for (int k2 = 0; k2 < 2; k2++) {
            bf16x8 pB = *reinterpret_cast<const bf16x8*>(&Pls[wave][1][lo][k2 * 32 + hi * 8]);
#pragma unroll
            for (int f = 0; f < 4; f++)
                accB[f] = __builtin_amdgcn_mfma_f32_16x16x32_bf16(pB, vB[k2 * 4 + f], accB[f], 0, 0, 0);
            if (aA) {
                bf16x8 pA = *reinterpret_cast<const bf16x8*>(&Pls[wave][0][lo][k2 * 32 + hi * 8]);
#pragma unroll
                for (int f = 0; f < 4; f++)
                    accA[f] = __builtin_amdgcn_mfma_f32_16x16x32_bf16(pA, vB[k2 * 4 + f], accA[f], 0, 0, 0);
            }
        }
    }

    // epilogue: row-sums across hi-groups, normalize, write y[b, q, h*64 + d]
    ssA += __shfl_xor(ssA, 16);  ssA += __shfl_xor(ssA, 32);
    ssB += __shfl_xor(ssB, 16);  ssB += __shfl_xor(ssB, 32);
#pragma unroll
    for (int r = 0; r < 4; r++) {
        float srA = __shfl(ssA, hi * 4 + r);
        float srB = __shfl(ssB, hi * 4 + r);
        float invA = 1.0f / srA, invB = 1.0f / srB;
        int qA = qwA + hi * 4 + r, qB = qwB + hi * 4 + r;
#pragma unroll
        for (int f = 0; f < 4; f++) {
            y[(size_t)(b * SEQ + qA) * DIMD + h * HD + f * 16 + lo] = (__bf16)(accA[f][r] * invA);
            y[(size_t)(b * SEQ + qB) * DIMD + h * HD + f * 16 + lo] = (__bf16)(accB[f][r] * invB);
        }
    }
}

// ---------------- launcher ----------------
extern "C" void kernel_launch(void* const* d_in, const int* in_sizes, int n_in,
                              void* d_out, int out_size, void* d_ws, size_t ws_size,
                              hipStream_t stream) {
    const float* x    = (const float*)d_in[0];
    const float* Wqkv = (const float*)d_in[1];
    const float* bqkv = (const float*)d_in[2];
    const float* Wout = (const float*)d_in[3];
    const float* bout = (const float*)d_in[4];
    float* out = (float*)d_out;

    char* ws = (char*)d_ws;
    __bf16* xb    = (__bf16*)(ws);                          // 8 MB  (x bf16; later reused as y)
    __bf16* wqkvT = (__bf16*)(ws + ((size_t)8  << 20));     // 3 MB  [1536][1024] (dead after GEMM1)
    __bf16* woutT = (__bf16*)(ws + ((size_t)11 << 20));     // 2 MB  [1024][1024]
    __bf16* qkvb  = (__bf16*)(ws + ((size_t)13 << 20));     // 12 MB [4096][1536]
    __bf16* vtg   = wqkvT;                                  // alias: 2.2 MB Vt[8][64][VSTR]
    __bf16* yb    = xb;                                     // alias: xb dead after GEMM1

    const int M = NB * SEQ;   // 4096

    cvt_f32_bf16<<<(M * DIMD / 4 + 255) / 256, 256, 0, stream>>>(x, xb, M * DIMD / 4);
    transpose_cvt<<<dim3(QKVN / 32, DIMD / 32), dim3(32, 8), 0, stream>>>(Wqkv, wqkvT, DIMD, QKVN);
    transpose_cvt<<<dim3(DIMD / 32, DIMD / 32), dim3(32, 8), 0, stream>>>(Wout, woutT, DIMD, DIMD);

    gemm_bf16<1, 1><<<dim3(QKVN / 128, M / 128), 256, 0, stream>>>(xb, wqkvT, bqkv, qkvb, M, QKVN, DIMD);

    transpose_v<<<dim3(SEQ / 32, HD / 32, NB * 4), dim3(32, 8), 0, stream>>>(qkvb, vtg);

    attn_fwd<<<512, 256, 0, stream>>>(qkvb, vtg, yb);

    gemm_bf16<0, 0><<<dim3(DIMD / 128, M / 128), 256, 0, stream>>>(yb, woutT, bout, out, M, DIMD, DIMD);
}

// Round 9
// 120.270 us; speedup vs baseline: 1.5617x; 1.3183x over previous
//
#include <hip/hip_runtime.h>
#include <cstdint>
#include <cstddef>

// ---------------- types ----------------
typedef __bf16 bf16x8 __attribute__((ext_vector_type(8)));
typedef __bf16 bf16x4 __attribute__((ext_vector_type(4)));
typedef float  f32x4  __attribute__((ext_vector_type(4)));

#define DIMD 1024
#define SEQ  2048
#define NB   2
#define NH   16
#define HD   64
#define QKVN 1536   // 1024 + 2*256
#define VOFF 1280   // DIMD + 256
#define VSTR 2080   // padded V^T row stride (4160B: breaks L2 channel aliasing)
#define CSC  0.18033688011112042f   // 0.125 * log2(e), folded into q in GEMM1

// async global->LDS (16B per lane, wave-uniform LDS base)
typedef __attribute__((address_space(1))) const void* as1_cvp;
typedef __attribute__((address_space(3))) void* as3_vp;
#define GLL16(g, l) __builtin_amdgcn_global_load_lds((as1_cvp)(const void*)(g), (as3_vp)(void*)(l), 16, 0, 0)

// ---------------- fp32 -> bf16 elementwise (vec4) ----------------
__global__ void cvt_f32_bf16(const float* __restrict__ in, __bf16* __restrict__ out, int n4) {
    int i = blockIdx.x * blockDim.x + threadIdx.x;
    if (i >= n4) return;
    float4 v = reinterpret_cast<const float4*>(in)[i];
    bf16x4 o;
    o[0] = (__bf16)v.x; o[1] = (__bf16)v.y; o[2] = (__bf16)v.z; o[3] = (__bf16)v.w;
    reinterpret_cast<bf16x4*>(out)[i] = o;
}

// ---------------- fp32 [R][C] -> bf16 [C][R] tiled transpose ----------------
__global__ void transpose_cvt(const float* __restrict__ in, __bf16* __restrict__ out, int R, int C) {
    __shared__ float t[32][33];
    int bx = blockIdx.x * 32;
    int by = blockIdx.y * 32;
    int tx = threadIdx.x, ty = threadIdx.y;   // (32, 8)
#pragma unroll
    for (int i = 0; i < 32; i += 8)
        t[ty + i][tx] = in[(size_t)(by + ty + i) * C + bx + tx];
    __syncthreads();
#pragma unroll
    for (int i = 0; i < 32; i += 8)
        out[(size_t)(bx + ty + i) * R + by + tx] = (__bf16)t[tx][ty + i];
}

// ---------------- bf16 [S][64] V-slice of qkv -> bf16 Vt[z][64][VSTR] ----------------
__global__ void transpose_v(const __bf16* __restrict__ qkv, __bf16* __restrict__ vtg) {
    __shared__ __bf16 t[32][34];
    const int z = blockIdx.z;           // b*4 + kh
    const int b = z >> 2, kh = z & 3;
    const int s0 = blockIdx.x * 32, d0 = blockIdx.y * 32;
    const int tx = threadIdx.x, ty = threadIdx.y;   // (32, 8)
    const __bf16* src = qkv + (size_t)b * SEQ * QKVN + VOFF + kh * HD;
#pragma unroll
    for (int i = 0; i < 32; i += 8)
        t[ty + i][tx] = src[(size_t)(s0 + ty + i) * QKVN + d0 + tx];
    __syncthreads();
    __bf16* dst = vtg + ((size_t)z * HD + d0) * VSTR + s0;
#pragma unroll
    for (int i = 0; i < 32; i += 8)
        dst[(size_t)(ty + i) * VSTR + tx] = t[tx][ty + i];
}

// ---------------- bf16 GEMM (m97 structure): C[M,N] = A[M,K]*Bt[N,K]^T + bias ----
// QSCALE: multiply cols < 1024 by CSC (pre-scales q for the attention kernel).
template<int OUT_BF16, int QSCALE>
__global__ __launch_bounds__(256) void gemm_bf16(
    const __bf16* __restrict__ A, const __bf16* __restrict__ Bt,
    const float* __restrict__ bias, void* __restrict__ Cout,
    int M, int N, int K)
{
    __shared__ __bf16 Als[128 * 32];   // linear: row*32 + k  (64B rows -> conflict-free b128)
    __shared__ __bf16 Bls[128 * 32];
    const int tid  = threadIdx.x;
    const int lane = tid & 63;
    const int wave = tid >> 6;
    const int lo = lane & 15, hi = lane >> 4;
    const int bm = blockIdx.y * 128, bn = blockIdx.x * 128;
    const int wr = (wave >> 1) * 64, wc = (wave & 1) * 64;

    const __bf16* gA = A  + (size_t)(bm + wave * 32 + (lane >> 2)) * K + (lane & 3) * 8;
    const __bf16* gB = Bt + (size_t)(bn + wave * 32 + (lane >> 2)) * K + (lane & 3) * 8;
    __bf16* lA = &Als[wave * 32 * 32];
    __bf16* lB = &Bls[wave * 32 * 32];

    f32x4 acc[4][4] = {};

    for (int k0 = 0; k0 < K; k0 += 32) {
        __syncthreads();
        GLL16(gA + k0,                  lA);
        GLL16(gA + k0 + (size_t)16 * K, lA + 512);
        GLL16(gB + k0,                  lB);
        GLL16(gB + k0 + (size_t)16 * K, lB + 512);
        __syncthreads();

        bf16x8 af[4], bfr[4];
#pragma unroll
        for (int i = 0; i < 4; i++) {
            af[i]  = *reinterpret_cast<const bf16x8*>(&Als[(wr + i * 16 + lo) * 32 + hi * 8]);
            bfr[i] = *reinterpret_cast<const bf16x8*>(&Bls[(wc + i * 16 + lo) * 32 + hi * 8]);
        }
#pragma unroll
        for (int i = 0; i < 4; i++)
#pragma unroll
            for (int j = 0; j < 4; j++)
                acc[i][j] = __builtin_amdgcn_mfma_f32_16x16x32_bf16(af[i], bfr[j], acc[i][j], 0, 0, 0);
    }

#pragma unroll
    for (int j = 0; j < 4; j++) {
        int col = bn + wc + j * 16 + lo;
        float bv = bias[col];
#pragma unroll
        for (int i = 0; i < 4; i++) {
            int row0 = bm + wr + i * 16 + hi * 4;
#pragma unroll
            for (int rr = 0; rr < 4; rr++) {
                float v = acc[i][j][rr] + bv;
                if (QSCALE && col < DIMD) v *= CSC;
                if (OUT_BF16) ((__bf16*)Cout)[(size_t)(row0 + rr) * N + col] = (__bf16)v;
                else          ((float* )Cout)[(size_t)(row0 + rr) * N + col] = v;
            }
        }
    }
}

// ---------------- causal GQA flash attention (LDS-staged K/V, paired dual tiles) ----
// 1D grid 512, 256 threads = 4 waves = the 4 q-heads of one kv-group; bid&7 =
// b*4+kh (XCD L2 pinning). Wave processes tiles A=p, B=127-p interleaved: every
// wave does exactly 33 chunk-computations. Per chunk, K[64][64] and Vt[64][64]
// are staged ONCE per block into double-buffered LDS via global_load_lds with
// XOR-pre-swizzled global source (linear LDS dest); fragment reads are then
// bank-even ds_read_b128. Prefetch of chunk c+1 is issued before computing c.
// Swapped QK^T (S^T = K*Q), fixed-max exp2 softmax (scores pre-scaled in GEMM1).
__global__ __launch_bounds__(256, 2) void attn_fwd(
    const __bf16* __restrict__ qkv, const __bf16* __restrict__ vt, __bf16* __restrict__ y)
{
    __shared__ __bf16 Kls[2][4096];        // [buf][row 64][8 x 16B units, swizzled]
    __shared__ __bf16 Vls[2][4096];        // same layout, rows = d
    __shared__ __bf16 Pls[4][2][16][72];   // [wave][tile][q][k], 144B rows
    const int tid  = threadIdx.x;
    const int wave = tid >> 6, lane = tid & 63;
    const int lo = lane & 15, hi = lane >> 4;

    const int bid = blockIdx.x;
    const int z  = bid & 7;              // b*4 + kh  -> XCD-pinned
    const int b  = z >> 2, kh = z & 3;
    const int p  = bid >> 3;             // 0..63
    const int h  = kh * 4 + wave;        // wave = head within kv-group

    const int TA = p, TB = 127 - p;
    const int qwA = TA * 16, qwB = TB * 16;
    const int cA = (TA >> 2) + 1, cB = (TB >> 2) + 1;   // cA <= 16 < 17 <= cB

    const __bf16* base = qkv + (size_t)b * SEQ * QKVN;
    const __bf16* qp = base + h * HD;
    const __bf16* kp = base + DIMD + kh * HD;
    const __bf16* vp = vt + (size_t)z * HD * VSTR;      // [64][VSTR]

    // ---- staging source addresses (XOR-pre-swizzled; LDS dest stays linear) ----
    // lane i of GLL instr n covers LDS row = n*8 + (i>>3), stored unit = i&7;
    // swizzle u_stored = u_orig ^ (row&7)  ->  u_orig = (i&7) ^ (i>>3).
    const int srow = lane >> 3;                 // 0..7
    const int sun  = ((lane & 7) ^ srow) * 8;   // source unit offset in elems
    const int r0 = wave * 16 + srow;            // rows for this wave's 2 instrs
    const int r1 = r0 + 8;
    const __bf16* kst0 = kp + (size_t)r0 * QKVN + sun;
    const __bf16* kst1 = kp + (size_t)r1 * QKVN + sun;
    const __bf16* vst0 = vp + (size_t)r0 * VSTR + sun;
    const __bf16* vst1 = vp + (size_t)r1 * VSTR + sun;
    // wave-uniform LDS dests (elems): instr n=2w at w*1024, n=2w+1 at +512
    __bf16* kd = &Kls[0][wave * 1024];
    __bf16* vd = &Vls[0][wave * 1024];

#define STAGE(kt, buf)                                              \
    do {                                                            \
        GLL16(kst0 + (size_t)(kt) * QKVN, kd + (buf) * 4096);       \
        GLL16(kst1 + (size_t)(kt) * QKVN, kd + (buf) * 4096 + 512); \
        GLL16(vst0 + (kt),                vd + (buf) * 4096);       \
        GLL16(vst1 + (kt),                vd + (buf) * 4096 + 512); \
    } while (0)

    // ---- swizzled fragment-read offsets (elems) ----
    const int xk = lo & 7;
    const int u0 = (hi ^ xk) * 8;          // units hi   (K frag0 / V k2=0)
    const int u1 = ((hi + 4) ^ xk) * 8;    // units hi+4 (K frag1 / V k2=1)
    const int lrow = lo * 64;

    // Q B-frags (pre-scaled by CSC in GEMM1): lane holds Q[qw+lo][hi*8..+8]
    bf16x8 bQA0 = *reinterpret_cast<const bf16x8*>(qp + (size_t)(qwA + lo) * QKVN + hi * 8);
    bf16x8 bQA1 = *reinterpret_cast<const bf16x8*>(qp + (size_t)(qwA + lo) * QKVN + 32 + hi * 8);
    bf16x8 bQB0 = *reinterpret_cast<const bf16x8*>(qp + (size_t)(qwB + lo) * QKVN + hi * 8);
    bf16x8 bQB1 = *reinterpret_cast<const bf16x8*>(qp + (size_t)(qwB + lo) * QKVN + 32 + hi * 8);

    f32x4 accA[4] = {}, accB[4] = {};
    float ssA = 0.0f, ssB = 0.0f;

    STAGE(0, 0);
    __syncthreads();   // drain: buf0 ready

    int cur = 0;
    for (int c = 0; c < cB; ++c) {
        const int kt = c << 6;
        if (c + 1 < cB) STAGE(kt + 64, cur ^ 1);   // issue early; hides under compute

        const bool aA = (c < cA);          // tile A active this chunk
        const bool dA = (c == cA - 1);     // tile A diagonal chunk
        const bool dB = (c == cB - 1);     // tile B diagonal chunk
        const __bf16* Kb = &Kls[cur][0];
        const __bf16* Vb = &Vls[cur][0];

        // S^T = K Q^T per 16-key subtile; lane gets q=lo, k = kt+16ks+hi*4+r
#pragma unroll
        for (int ks = 0; ks < 4; ks++) {
            bf16x8 aK0 = *reinterpret_cast<const bf16x8*>(Kb + ks * 1024 + lrow + u0);
            bf16x8 aK1 = *reinterpret_cast<const bf16x8*>(Kb + ks * 1024 + lrow + u1);

            {   // tile B (always active)
                f32x4 s = {0.f, 0.f, 0.f, 0.f};
                s = __builtin_amdgcn_mfma_f32_16x16x32_bf16(aK0, bQB0, s, 0, 0, 0);
                s = __builtin_amdgcn_mfma_f32_16x16x32_bf16(aK1, bQB1, s, 0, 0, 0);
                bf16x4 pk;
#pragma unroll
                for (int r = 0; r < 4; r++) {
                    float e = exp2f(s[r]);
                    if (dB && (kt + ks * 16 + hi * 4 + r > qwB + lo)) e = 0.0f;
                    ssB += e;
                    pk[r] = (__bf16)e;
                }
                *reinterpret_cast<bf16x4*>(&Pls[wave][1][lo][ks * 16 + hi * 4]) = pk;
            }
            if (aA) {   // tile A (prefix only) — reuses aK0/aK1
                f32x4 s = {0.f, 0.f, 0.f, 0.f};
                s = __builtin_amdgcn_mfma_f32_16x16x32_bf16(aK0, bQA0, s, 0, 0, 0);
                s = __builtin_amdgcn_mfma_f32_16x16x32_bf16(aK1, bQA1, s, 0, 0, 0);
                bf16x4 pk;
#pragma unroll
                for (int r = 0; r < 4; r++) {
                    float e = exp2f(s[r]);
                    if (dA && (kt + ks * 16 + hi * 4 + r > qwA + lo)) e = 0.0f;
                    ssA += e;
                    pk[r] = (__bf16)e;
                }
                *reinterpret_cast<bf16x4*>(&Pls[wave][0][lo][ks * 16 + hi * 4]) = pk;
            }
        }

        // P x V : V frags from swizzled LDS, shared by both tiles
#pragma unroll
        for (int k2 = 0; k2 < 2; k2++) {
            const int uv = k2 ? u1 : u0;
            bf16x8 v0 = *reinterpret_cast<const bf16x8*>(Vb + 0 * 1024 + lrow + uv);
            bf16x8 v1 = *reinterpret_cast<const bf16x8*>(Vb + 1 * 1024 + lrow + uv);
            bf16x8 v2 = *reinterpret_cast<const bf16x8*>(Vb + 2 * 1024 + lrow + uv);
            bf16x8 v3 = *reinterpret_cast<const bf16x8*>(Vb + 3 * 1024 + lrow + uv);
            bf16x8 pB = *reinterpret_cast<const bf16x8*>(&Pls[wave][1][lo][k2 * 32 + hi * 8]);
            accB[0] = __builtin_amdgcn_mfma_f32_16x16x32_bf16(pB, v0, accB[0], 0, 0, 0);
            accB[1] = __builtin_amdgcn_mfma_f32_16x16x32_bf16(pB, v1, accB[1], 0, 0, 0);
            accB[2] = __builtin_amdgcn_mfma_f32_16x16x32_bf16(pB, v2, accB[2], 0, 0, 0);
            accB[3] = __builtin_amdgcn_mfma_f32_16x16x32_bf16(pB, v3, accB[3], 0, 0, 0);
            if (aA) {
                bf16x8 pA = *reinterpret_cast<const bf16x8*>(&Pls[wave][0][lo][k2 * 32 + hi * 8]);
                accA[0] = __builtin_amdgcn_mfma_f32_16x16x32_bf16(pA, v0, accA[0], 0, 0, 0);
                accA[1] = __builtin_amdgcn_mfma_f32_16x16x32_bf16(pA, v1, accA[1], 0, 0, 0);
                accA[2] = __builtin_amdgcn_mfma_f32_16x16x32_bf16(pA, v2, accA[2], 0, 0, 0);
                accA[3] = __builtin_amdgcn_mfma_f32_16x16x32_bf16(pA, v3, accA[3], 0, 0, 0);
            }
        }

        __syncthreads();   // buf(cur^1) staged & everyone done with buf(cur)
        cur ^= 1;
    }
#undef STAGE

    // epilogue: row-sums across hi-groups, normalize, write y[b, q, h*64 + d]
    ssA += __shfl_xor(ssA, 16);  ssA += __shfl_xor(ssA, 32);
    ssB += __shfl_xor(ssB, 16);  ssB += __shfl_xor(ssB, 32);
#pragma unroll
    for (int r = 0; r < 4; r++) {
        float srA = __shfl(ssA, hi * 4 + r);
        float srB = __shfl(ssB, hi * 4 + r);
        float invA = 1.0f / srA, invB = 1.0f / srB;
        int qA = qwA + hi * 4 + r, qB = qwB + hi * 4 + r;
#pragma unroll
        for (int f = 0; f < 4; f++) {
            y[(size_t)(b * SEQ + qA) * DIMD + h * HD + f * 16 + lo] = (__bf16)(accA[f][r] * invA);
            y[(size_t)(b * SEQ + qB) * DIMD + h * HD + f * 16 + lo] = (__bf16)(accB[f][r] * invB);
        }
    }
}

// ---------------- launcher ----------------
extern "C" void kernel_launch(void* const* d_in, const int* in_sizes, int n_in,
                              void* d_out, int out_size, void* d_ws, size_t ws_size,
                              hipStream_t stream) {
    const float* x    = (const float*)d_in[0];
    const float* Wqkv = (const float*)d_in[1];
    const float* bqkv = (const float*)d_in[2];
    const float* Wout = (const float*)d_in[3];
    const float* bout = (const float*)d_in[4];
    float* out = (float*)d_out;

    char* ws = (char*)d_ws;
    __bf16* xb    = (__bf16*)(ws);                          // 8 MB  (x bf16; later reused as y)
    __bf16* wqkvT = (__bf16*)(ws + ((size_t)8  << 20));     // 3 MB  [1536][1024] (dead after GEMM1)
    __bf16* woutT = (__bf16*)(ws + ((size_t)11 << 20));     // 2 MB  [1024][1024]
    __bf16* qkvb  = (__bf16*)(ws + ((size_t)13 << 20));     // 12 MB [4096][1536]
    __bf16* vtg   = wqkvT;                                  // alias: 2.2 MB Vt[8][64][VSTR]
    __bf16* yb    = xb;                                     // alias: xb dead after GEMM1

    const int M = NB * SEQ;   // 4096

    cvt_f32_bf16<<<(M * DIMD / 4 + 255) / 256, 256, 0, stream>>>(x, xb, M * DIMD / 4);
    transpose_cvt<<<dim3(QKVN / 32, DIMD / 32), dim3(32, 8), 0, stream>>>(Wqkv, wqkvT, DIMD, QKVN);
    transpose_cvt<<<dim3(DIMD / 32, DIMD / 32), dim3(32, 8), 0, stream>>>(Wout, woutT, DIMD, DIMD);

    gemm_bf16<1, 1><<<dim3(QKVN / 128, M / 128), 256, 0, stream>>>(xb, wqkvT, bqkv, qkvb, M, QKVN, DIMD);

    transpose_v<<<dim3(SEQ / 32, HD / 32, NB * 4), dim3(32, 8), 0, stream>>>(qkvb, vtg);

    attn_fwd<<<512, 256, 0, stream>>>(qkvb, vtg, yb);

    gemm_bf16<0, 0><<<dim3(DIMD / 128, M / 128), 256, 0, stream>>>(yb, woutT, bout, out, M, DIMD, DIMD);
}

// Round 10
// 116.674 us; speedup vs baseline: 1.6098x; 1.0308x over previous
//
#include <hip/hip_runtime.h>
#include <cstdint>
#include <cstddef>

// ---------------- types ----------------
typedef __bf16 bf16x8 __attribute__((ext_vector_type(8)));
typedef __bf16 bf16x4 __attribute__((ext_vector_type(4)));
typedef float  f32x4  __attribute__((ext_vector_type(4)));

#define DIMD 1024
#define SEQ  2048
#define NB   2
#define NH   16
#define HD   64
#define QKVN 1536   // 1024 + 2*256
#define VOFF 1280   // DIMD + 256
#define VSTR 2080   // padded V^T row stride (4160B: breaks L2 channel aliasing)
#define CSC  0.18033688011112042f   // 0.125 * log2(e), folded into q in GEMM1

// async global->LDS (16B per lane, wave-uniform LDS base)
typedef __attribute__((address_space(1))) const void* as1_cvp;
typedef __attribute__((address_space(3))) void* as3_vp;
#define GLL16(g, l) __builtin_amdgcn_global_load_lds((as1_cvp)(const void*)(g), (as3_vp)(void*)(l), 16, 0, 0)

// ---------------- fp32 -> bf16 elementwise (vec4) ----------------
__global__ void cvt_f32_bf16(const float* __restrict__ in, __bf16* __restrict__ out, int n4) {
    int i = blockIdx.x * blockDim.x + threadIdx.x;
    if (i >= n4) return;
    float4 v = reinterpret_cast<const float4*>(in)[i];
    bf16x4 o;
    o[0] = (__bf16)v.x; o[1] = (__bf16)v.y; o[2] = (__bf16)v.z; o[3] = (__bf16)v.w;
    reinterpret_cast<bf16x4*>(out)[i] = o;
}

// ---------------- fp32 [R][C] -> bf16 [C][R] tiled transpose ----------------
__global__ void transpose_cvt(const float* __restrict__ in, __bf16* __restrict__ out, int R, int C) {
    __shared__ float t[32][33];
    int bx = blockIdx.x * 32;
    int by = blockIdx.y * 32;
    int tx = threadIdx.x, ty = threadIdx.y;   // (32, 8)
#pragma unroll
    for (int i = 0; i < 32; i += 8)
        t[ty + i][tx] = in[(size_t)(by + ty + i) * C + bx + tx];
    __syncthreads();
#pragma unroll
    for (int i = 0; i < 32; i += 8)
        out[(size_t)(bx + ty + i) * R + by + tx] = (__bf16)t[tx][ty + i];
}

// ---------------- bf16 [S][64] V-slice of qkv -> bf16 Vt[z][64][VSTR] ----------------
__global__ void transpose_v(const __bf16* __restrict__ qkv, __bf16* __restrict__ vtg) {
    __shared__ __bf16 t[32][34];
    const int z = blockIdx.z;           // b*4 + kh
    const int b = z >> 2, kh = z & 3;
    const int s0 = blockIdx.x * 32, d0 = blockIdx.y * 32;
    const int tx = threadIdx.x, ty = threadIdx.y;   // (32, 8)
    const __bf16* src = qkv + (size_t)b * SEQ * QKVN + VOFF + kh * HD;
#pragma unroll
    for (int i = 0; i < 32; i += 8)
        t[ty + i][tx] = src[(size_t)(s0 + ty + i) * QKVN + d0 + tx];
    __syncthreads();
    __bf16* dst = vtg + ((size_t)z * HD + d0) * VSTR + s0;
#pragma unroll
    for (int i = 0; i < 32; i += 8)
        dst[(size_t)(ty + i) * VSTR + tx] = t[tx][ty + i];
}

// ---------------- bf16 GEMM (m97 structure): C[M,N] = A[M,K]*Bt[N,K]^T + bias ----
// QSCALE: multiply cols < 1024 by CSC (pre-scales q for the attention kernel).
template<int OUT_BF16, int QSCALE>
__global__ __launch_bounds__(256) void gemm_bf16(
    const __bf16* __restrict__ A, const __bf16* __restrict__ Bt,
    const float* __restrict__ bias, void* __restrict__ Cout,
    int M, int N, int K)
{
    __shared__ __bf16 Als[128 * 32];   // linear: row*32 + k  (64B rows -> conflict-free b128)
    __shared__ __bf16 Bls[128 * 32];
    const int tid  = threadIdx.x;
    const int lane = tid & 63;
    const int wave = tid >> 6;
    const int lo = lane & 15, hi = lane >> 4;
    const int bm = blockIdx.y * 128, bn = blockIdx.x * 128;
    const int wr = (wave >> 1) * 64, wc = (wave & 1) * 64;

    const __bf16* gA = A  + (size_t)(bm + wave * 32 + (lane >> 2)) * K + (lane & 3) * 8;
    const __bf16* gB = Bt + (size_t)(bn + wave * 32 + (lane >> 2)) * K + (lane & 3) * 8;
    __bf16* lA = &Als[wave * 32 * 32];
    __bf16* lB = &Bls[wave * 32 * 32];

    f32x4 acc[4][4] = {};

    for (int k0 = 0; k0 < K; k0 += 32) {
        __syncthreads();
        GLL16(gA + k0,                  lA);
        GLL16(gA + k0 + (size_t)16 * K, lA + 512);
        GLL16(gB + k0,                  lB);
        GLL16(gB + k0 + (size_t)16 * K, lB + 512);
        __syncthreads();

        bf16x8 af[4], bfr[4];
#pragma unroll
        for (int i = 0; i < 4; i++) {
            af[i]  = *reinterpret_cast<const bf16x8*>(&Als[(wr + i * 16 + lo) * 32 + hi * 8]);
            bfr[i] = *reinterpret_cast<const bf16x8*>(&Bls[(wc + i * 16 + lo) * 32 + hi * 8]);
        }
#pragma unroll
        for (int i = 0; i < 4; i++)
#pragma unroll
            for (int j = 0; j < 4; j++)
                acc[i][j] = __builtin_amdgcn_mfma_f32_16x16x32_bf16(af[i], bfr[j], acc[i][j], 0, 0, 0);
    }

#pragma unroll
    for (int j = 0; j < 4; j++) {
        int col = bn + wc + j * 16 + lo;
        float bv = bias[col];
#pragma unroll
        for (int i = 0; i < 4; i++) {
            int row0 = bm + wr + i * 16 + hi * 4;
#pragma unroll
            for (int rr = 0; rr < 4; rr++) {
                float v = acc[i][j][rr] + bv;
                if (QSCALE && col < DIMD) v *= CSC;
                if (OUT_BF16) ((__bf16*)Cout)[(size_t)(row0 + rr) * N + col] = (__bf16)v;
                else          ((float* )Cout)[(size_t)(row0 + rr) * N + col] = v;
            }
        }
    }
}

// ---------------- causal GQA flash attention (in-block split-K, 8 waves) ----------------
// 1D grid 512, 512 threads = 8 waves = 4 heads x 2 key-parities. bid&7 = b*4+kh
// (XCD L2 pinning). Each wave handles tiles A=p, B=127-p (16 q-rows each) over its
// parity's 64-key chunks (chunk index ce = 2s+par). 128-key super-chunks staged once
// per block (K[128][64], Vt[64][128], XOR-swizzled source, single-buffered).
// Fixed-max exp2 softmax (scores pre-scaled by CSC in GEMM1) makes split-K a pure
// sum: parity partials (accO, ssum) combine by addition through LDS at the end.
__global__ __launch_bounds__(512, 4) void attn_fwd(
    const __bf16* __restrict__ qkv, const __bf16* __restrict__ vt, __bf16* __restrict__ y)
{
    __shared__ __bf16 Kls[128 * 64];        // [key][d], row-XOR-swizzled 16B units
    __shared__ __bf16 Vls[64 * 128];        // [d][key], row-XOR-swizzled 16B units
    __shared__ __bf16 Pls[8][2][16][72];    // [wave][tile][q][k], 144B rows
    const int tid  = threadIdx.x;
    const int wave = tid >> 6, lane = tid & 63;
    const int lo = lane & 15, hi = lane >> 4;
    const int head = wave & 3, par = wave >> 2;

    const int bid = blockIdx.x;
    const int z  = bid & 7;              // b*4 + kh  -> XCD-pinned
    const int b  = z >> 2, kh = z & 3;
    const int p  = bid >> 3;             // 0..63
    const int h  = kh * 4 + head;

    const int TA = p, TB = 127 - p;
    const int qwA = TA * 16, qwB = TB * 16;
    const int cA = (TA >> 2) + 1, cB = (TB >> 2) + 1;   // 64-key chunk counts
    const int nsc = (cB + 1) >> 1;                      // 128-key super-chunks

    const __bf16* base = qkv + (size_t)b * SEQ * QKVN;
    const __bf16* qp = base + h * HD;
    const __bf16* kp = base + DIMD + kh * HD;
    const __bf16* vp = vt + (size_t)z * HD * VSTR;      // [64][VSTR]

    // ---- staging sources (XOR-pre-swizzled; LDS dest linear) ----
    // K: wave w stages key rows [16w,16w+16); instr lane covers row base+(i>>3), unit i&7.
    const int srow = lane >> 3;                       // 0..7
    const int sun  = ((lane & 7) ^ srow) * 8;
    const __bf16* kst0 = kp + (size_t)(wave * 16 + srow) * QKVN + sun;
    const __bf16* kst1 = kp + (size_t)(wave * 16 + 8 + srow) * QKVN + sun;
    // V: wave w stages d rows [8w,8w+8); instr lane covers row base+(i>>4), unit i&15.
    const int vrow = lane >> 4;                       // 0..3
    const int vun0 = ((lane & 15) ^ vrow) * 8;
    const int vun1 = ((lane & 15) ^ (vrow + 4)) * 8;
    const __bf16* vst0 = vp + (size_t)(wave * 8 + vrow) * VSTR + vun0;
    const __bf16* vst1 = vp + (size_t)(wave * 8 + 4 + vrow) * VSTR + vun1;
    __bf16* kdst = &Kls[wave * 1024];
    __bf16* vdst = &Vls[wave * 1024];

#define STAGE(s)                                            \
    do {                                                    \
        const size_t ko = (size_t)(s) * 128 * QKVN;         \
        const int    vo = (s) * 128;                        \
        GLL16(kst0 + ko, kdst);                             \
        GLL16(kst1 + ko, kdst + 512);                       \
        GLL16(vst0 + vo, vdst);                             \
        GLL16(vst1 + vo, vdst + 512);                       \
    } while (0)

    // ---- swizzled fragment-read offsets ----
    const int xk = lo & 7;
    const int u0 = (hi ^ xk) * 8;          // K d-units hi
    const int u1 = ((hi + 4) ^ xk) * 8;    // K d-units hi+4
    const int kb = par * 64;               // this parity's key base within tile

    // Q B-frags (pre-scaled by CSC in GEMM1): lane holds Q[qw+lo][hi*8..+8]
    bf16x8 bQA0 = *reinterpret_cast<const bf16x8*>(qp + (size_t)(qwA + lo) * QKVN + hi * 8);
    bf16x8 bQA1 = *reinterpret_cast<const bf16x8*>(qp + (size_t)(qwA + lo) * QKVN + 32 + hi * 8);
    bf16x8 bQB0 = *reinterpret_cast<const bf16x8*>(qp + (size_t)(qwB + lo) * QKVN + hi * 8);
    bf16x8 bQB1 = *reinterpret_cast<const bf16x8*>(qp + (size_t)(qwB + lo) * QKVN + 32 + hi * 8);

    f32x4 accA[4] = {}, accB[4] = {};
    float ssA = 0.0f, ssB = 0.0f;

    STAGE(0);
    __syncthreads();

    for (int s = 0; s < nsc; ++s) {
        const int ce = 2 * s + par;        // this wave's 64-key chunk index
        const int kt = ce << 6;            // global key base (mask arithmetic)
        const bool aB = (ce < cB), dB = (ce == cB - 1);
        const bool aA = (ce < cA), dA = (ce == cA - 1);

        if (aB) {
            // S^T = K Q^T per 16-key subtile; lane gets q=lo, k = kt+16ks+hi*4+r
#pragma unroll
            for (int ks = 0; ks < 4; ks++) {
                const __bf16* Kr = &Kls[(kb + ks * 16 + lo) * 64];
                bf16x8 aK0 = *reinterpret_cast<const bf16x8*>(Kr + u0);
                bf16x8 aK1 = *reinterpret_cast<const bf16x8*>(Kr + u1);

                {   // tile B
                    f32x4 sv = {0.f, 0.f, 0.f, 0.f};
                    sv = __builtin_amdgcn_mfma_f32_16x16x32_bf16(aK0, bQB0, sv, 0, 0, 0);
                    sv = __builtin_amdgcn_mfma_f32_16x16x32_bf16(aK1, bQB1, sv, 0, 0, 0);
                    bf16x4 pk;
#pragma unroll
                    for (int r = 0; r < 4; r++) {
                        float e = exp2f(sv[r]);
                        if (dB && (kt + ks * 16 + hi * 4 + r > qwB + lo)) e = 0.0f;
                        ssB += e;
                        pk[r] = (__bf16)e;
                    }
                    *reinterpret_cast<bf16x4*>(&Pls[wave][1][lo][ks * 16 + hi * 4]) = pk;
                }
                if (aA) {   // tile A — reuses aK0/aK1
                    f32x4 sv = {0.f, 0.f, 0.f, 0.f};
                    sv = __builtin_amdgcn_mfma_f32_16x16x32_bf16(aK0, bQA0, sv, 0, 0, 0);
                    sv = __builtin_amdgcn_mfma_f32_16x16x32_bf16(aK1, bQA1, sv, 0, 0, 0);
                    bf16x4 pk;
#pragma unroll
                    for (int r = 0; r < 4; r++) {
                        float e = exp2f(sv[r]);
                        if (dA && (kt + ks * 16 + hi * 4 + r > qwA + lo)) e = 0.0f;
                        ssA += e;
                        pk[r] = (__bf16)e;
                    }
                    *reinterpret_cast<bf16x4*>(&Pls[wave][0][lo][ks * 16 + hi * 4]) = pk;
                }
            }

            // P x V : V frags shared by both tiles
#pragma unroll
            for (int k2 = 0; k2 < 2; k2++) {
                const int uv = ((8 * par + k2 * 4 + hi) ^ xk) * 8;
                bf16x8 v0 = *reinterpret_cast<const bf16x8*>(&Vls[(0 * 16 + lo) * 128] + uv);
                bf16x8 v1 = *reinterpret_cast<const bf16x8*>(&Vls[(1 * 16 + lo) * 128] + uv);
                bf16x8 v2 = *reinterpret_cast<const bf16x8*>(&Vls[(2 * 16 + lo) * 128] + uv);
                bf16x8 v3 = *reinterpret_cast<const bf16x8*>(&Vls[(3 * 16 + lo) * 128] + uv);
                bf16x8 pB = *reinterpret_cast<const bf16x8*>(&Pls[wave][1][lo][k2 * 32 + hi * 8]);
                accB[0] = __builtin_amdgcn_mfma_f32_16x16x32_bf16(pB, v0, accB[0], 0, 0, 0);
                accB[1] = __builtin_amdgcn_mfma_f32_16x16x32_bf16(pB, v1, accB[1], 0, 0, 0);
                accB[2] = __builtin_amdgcn_mfma_f32_16x16x32_bf16(pB, v2, accB[2], 0, 0, 0);
                accB[3] = __builtin_amdgcn_mfma_f32_16x16x32_bf16(pB, v3, accB[3], 0, 0, 0);
                if (aA) {
                    bf16x8 pA = *reinterpret_cast<const bf16x8*>(&Pls[wave][0][lo][k2 * 32 + hi * 8]);
                    accA[0] = __builtin_amdgcn_mfma_f32_16x16x32_bf16(pA, v0, accA[0], 0, 0, 0);
                    accA[1] = __builtin_amdgcn_mfma_f32_16x16x32_bf16(pA, v1, accA[1], 0, 0, 0);
                    accA[2] = __builtin_amdgcn_mfma_f32_16x16x32_bf16(pA, v2, accA[2], 0, 0, 0);
                    accA[3] = __builtin_amdgcn_mfma_f32_16x16x32_bf16(pA, v3, accA[3], 0, 0, 0);
                }
            }
        }

        __syncthreads();                       // all reads of this super-chunk done
        if (s + 1 < nsc) {
            STAGE(s + 1);
            __syncthreads();                   // staged data visible
        }
    }
#undef STAGE

    // ---- parity combine (pure sum: fixed-max softmax) through LDS (overlays Pls) ----
    float* cls = (float*)&Pls[0][0][0][0];
    const int cbase = (head * 64 + lane) * 36;   // 144B stride, 16B-aligned
    if (par == 1) {
#pragma unroll
        for (int f = 0; f < 4; f++) {
            *reinterpret_cast<f32x4*>(&cls[cbase + f * 4])      = accA[f];
            *reinterpret_cast<f32x4*>(&cls[cbase + 16 + f * 4]) = accB[f];
        }
        cls[cbase + 32] = ssA;
        cls[cbase + 33] = ssB;
    }
    __syncthreads();
    if (par == 0) {
#pragma unroll
        for (int f = 0; f < 4; f++) {
            accA[f] += *reinterpret_cast<f32x4*>(&cls[cbase + f * 4]);
            accB[f] += *reinterpret_cast<f32x4*>(&cls[cbase + 16 + f * 4]);
        }
        ssA += cls[cbase + 32];
        ssB += cls[cbase + 33];

        ssA += __shfl_xor(ssA, 16);  ssA += __shfl_xor(ssA, 32);
        ssB += __shfl_xor(ssB, 16);  ssB += __shfl_xor(ssB, 32);
#pragma unroll
        for (int r = 0; r < 4; r++) {
            float srA = __shfl(ssA, hi * 4 + r);
            float srB = __shfl(ssB, hi * 4 + r);
            float invA = 1.0f / srA, invB = 1.0f / srB;
            int qA = qwA + hi * 4 + r, qB = qwB + hi * 4 + r;
#pragma unroll
            for (int f = 0; f < 4; f++) {
                y[(size_t)(b * SEQ + qA) * DIMD + h * HD + f * 16 + lo] = (__bf16)(accA[f][r] * invA);
                y[(size_t)(b * SEQ + qB) * DIMD + h * HD + f * 16 + lo] = (__bf16)(accB[f][r] * invB);
            }
        }
    }
}

// ---------------- launcher ----------------
extern "C" void kernel_launch(void* const* d_in, const int* in_sizes, int n_in,
                              void* d_out, int out_size, void* d_ws, size_t ws_size,
                              hipStream_t stream) {
    const float* x    = (const float*)d_in[0];
    const float* Wqkv = (const float*)d_in[1];
    const float* bqkv = (const float*)d_in[2];
    const float* Wout = (const float*)d_in[3];
    const float* bout = (const float*)d_in[4];
    float* out = (float*)d_out;

    char* ws = (char*)d_ws;
    __bf16* xb    = (__bf16*)(ws);                          // 8 MB  (x bf16; later reused as y)
    __bf16* wqkvT = (__bf16*)(ws + ((size_t)8  << 20));     // 3 MB  [1536][1024] (dead after GEMM1)
    __bf16* woutT = (__bf16*)(ws + ((size_t)11 << 20));     // 2 MB  [1024][1024]
    __bf16* qkvb  = (__bf16*)(ws + ((size_t)13 << 20));     // 12 MB [4096][1536]
    __bf16* vtg   = wqkvT;                                  // alias: 2.2 MB Vt[8][64][VSTR]
    __bf16* yb    = xb;                                     // alias: xb dead after GEMM1

    const int M = NB * SEQ;   // 4096

    cvt_f32_bf16<<<(M * DIMD / 4 + 255) / 256, 256, 0, stream>>>(x, xb, M * DIMD / 4);
    transpose_cvt<<<dim3(QKVN / 32, DIMD / 32), dim3(32, 8), 0, stream>>>(Wqkv, wqkvT, DIMD, QKVN);
    transpose_cvt<<<dim3(DIMD / 32, DIMD / 32), dim3(32, 8), 0, stream>>>(Wout, woutT, DIMD, DIMD);

    gemm_bf16<1, 1><<<dim3(QKVN / 128, M / 128), 256, 0, stream>>>(xb, wqkvT, bqkv, qkvb, M, QKVN, DIMD);

    transpose_v<<<dim3(SEQ / 32, HD / 32, NB * 4), dim3(32, 8), 0, stream>>>(qkvb, vtg);

    attn_fwd<<<512, 512, 0, stream>>>(qkvb, vtg, yb);

    gemm_bf16<0, 0><<<dim3(DIMD / 128, M / 128), 256, 0, stream>>>(yb, woutT, bout, out, M, DIMD, DIMD);
}